// Round 1
// baseline (9024.417 us; speedup 1.0000x reference)
//
#include <hip/hip_runtime.h>
#include <math.h>

#define HIDDEN 2048
#define TSTEPS 1024
#define NWG 256
#define TPB 512
#define UPW 8        // hidden units per WG
#define CPT 16       // columns per thread

__device__ __forceinline__ float sigmoidf_(float x) { return 1.0f / (1.0f + __expf(-x)); }

__global__ __launch_bounds__(TPB, 2)
void lstm_persistent(const float* __restrict__ features,
                     const float* __restrict__ pc,
                     const float* __restrict__ W_ih,
                     const float* __restrict__ W_hh,
                     const float* __restrict__ b_ih,
                     const float* __restrict__ b_hh,
                     const float* __restrict__ W_fc,
                     const float* __restrict__ b_fc,
                     float* __restrict__ out,
                     float* __restrict__ hbuf,   // 2*HIDDEN floats in ws
                     int*   __restrict__ flags)  // NWG ints in ws (memset 0 before launch)
{
    const int b    = blockIdx.x;
    const int t    = threadIdx.x;
    const int g    = t & 3;        // gate index 0..3 (i,f,g,o)
    const int cc   = t >> 2;       // column-chunk 0..127
    const int col0 = cc * CPT;
    const int lane = t & 63;
    const int wave = t >> 6;

    __shared__ float h_sh[HIDDEN];
    __shared__ float pc_sh[2 * TSTEPS];
    __shared__ float red[8 * 32];
    __shared__ float outred[8 * 2];
    __shared__ float c_sh[UPW];

    // ---- one-time staging ----
    // point cloud -> LDS (2048 floats, 512 threads x float4)
    {
        const float4* p4 = reinterpret_cast<const float4*>(pc);
        reinterpret_cast<float4*>(pc_sh)[t] = p4[t];
    }
    if (t < UPW) c_sh[t] = 0.0f;

    // W_hh slice -> registers: w[ji][k] = W_hh[g*2048 + b*8 + ji][col0 + k]
    float w[UPW][CPT];
    {
        const int baserow = g * HIDDEN + b * UPW;
        #pragma unroll
        for (int ji = 0; ji < UPW; ++ji) {
            const float4* src = reinterpret_cast<const float4*>(
                W_hh + (size_t)(baserow + ji) * HIDDEN + col0);
            float4 a0 = src[0], a1 = src[1], a2 = src[2], a3 = src[3];
            w[ji][0]  = a0.x; w[ji][1]  = a0.y; w[ji][2]  = a0.z; w[ji][3]  = a0.w;
            w[ji][4]  = a1.x; w[ji][5]  = a1.y; w[ji][6]  = a1.z; w[ji][7]  = a1.w;
            w[ji][8]  = a2.x; w[ji][9]  = a2.y; w[ji][10] = a2.z; w[ji][11] = a2.w;
            w[ji][12] = a3.x; w[ji][13] = a3.y; w[ji][14] = a3.z; w[ji][15] = a3.w;
        }
    }

    // per-row constants for wave 0 (row id = lane&31: g' = l>>3, ji = l&7)
    float bias_r, wi0_r, wi1_r;
    {
        const int l   = lane & 31;
        const int row = (l >> 3) * HIDDEN + b * UPW + (l & 7);
        bias_r = b_ih[row] + b_hh[row];
        wi0_r  = W_ih[row * 2 + 0];
        wi1_r  = W_ih[row * 2 + 1];
    }
    __syncthreads();

    // ---- recurrence ----
    for (int s = 0; s < TSTEPS; ++s) {
        const float* hsrc = (s == 0) ? features : (hbuf + (s & 1) * HIDDEN);
        float*       hdst = hbuf + ((s + 1) & 1) * HIDDEN;

        // stage h (agent-scope loads: cross-XCD coherent)
        {
            const int i0 = t * 4;
            float* p = (float*)hsrc;
            float v0 = __hip_atomic_load(p + i0 + 0, __ATOMIC_RELAXED, __HIP_MEMORY_SCOPE_AGENT);
            float v1 = __hip_atomic_load(p + i0 + 1, __ATOMIC_RELAXED, __HIP_MEMORY_SCOPE_AGENT);
            float v2 = __hip_atomic_load(p + i0 + 2, __ATOMIC_RELAXED, __HIP_MEMORY_SCOPE_AGENT);
            float v3 = __hip_atomic_load(p + i0 + 3, __ATOMIC_RELAXED, __HIP_MEMORY_SCOPE_AGENT);
            h_sh[i0 + 0] = v0; h_sh[i0 + 1] = v1; h_sh[i0 + 2] = v2; h_sh[i0 + 3] = v3;
        }
        __syncthreads();

        // fc output for step s-1 (h_sh currently holds h after s updates)
        if (s >= 1 && b == ((s - 1) & 255)) {
            float po0 = 0.0f, po1 = 0.0f;
            #pragma unroll
            for (int k = 0; k < CPT; ++k) {
                float hv = h_sh[col0 + k];
                po0 += hv * W_fc[col0 + k];
                po1 += hv * W_fc[HIDDEN + col0 + k];
            }
            #pragma unroll
            for (int m = 1; m < 64; m <<= 1) {
                po0 += __shfl_xor(po0, m);
                po1 += __shfl_xor(po1, m);
            }
            if (lane == 0) { outred[wave * 2 + 0] = po0; outred[wave * 2 + 1] = po1; }
            __syncthreads();
            if (t == 0) {
                float o0 = 0.0f, o1 = 0.0f;
                #pragma unroll
                for (int ww = 0; ww < 8; ++ww) { o0 += outred[ww * 2]; o1 += outred[ww * 2 + 1]; }
                out[(s - 1) * 2 + 0] = 0.25f * o0 + b_fc[0];
                out[(s - 1) * 2 + 1] = 0.25f * o1 + b_fc[1];
            }
        }

        // load my h chunk from LDS
        float hr[CPT];
        #pragma unroll
        for (int k = 0; k < CPT; k += 4) {
            float4 hv = *reinterpret_cast<const float4*>(h_sh + col0 + k);
            hr[k] = hv.x; hr[k + 1] = hv.y; hr[k + 2] = hv.z; hr[k + 3] = hv.w;
        }

        // 128 FMAs: acc[ji] += w[ji][k] * h[col0+k]
        float acc[UPW];
        #pragma unroll
        for (int ji = 0; ji < UPW; ++ji) acc[ji] = 0.0f;
        #pragma unroll
        for (int k = 0; k < CPT; ++k) {
            #pragma unroll
            for (int ji = 0; ji < UPW; ++ji) acc[ji] += w[ji][k] * hr[k];
        }

        // intra-wave reduce across column-chunks (lanes sharing l&3)
        #pragma unroll
        for (int m = 4; m < 64; m <<= 1) {
            #pragma unroll
            for (int ji = 0; ji < UPW; ++ji) acc[ji] += __shfl_xor(acc[ji], m);
        }
        if (lane < 4) {
            #pragma unroll
            for (int ji = 0; ji < UPW; ++ji) red[wave * 32 + lane * 8 + ji] = acc[ji];
        }
        __syncthreads();

        // final reduce + gates on wave 0
        if (wave == 0) {
            const int l = lane & 31;   // row id: g' = l>>3, ji = l&7
            float sum = 0.0f;
            #pragma unroll
            for (int ww = 0; ww < 8; ++ww) sum += red[ww * 32 + l];
            const float x0 = pc_sh[2 * s], x1 = pc_sh[2 * s + 1];
            const float gate = sum + bias_r + wi0_r * x0 + wi1_r * x1;
            // gather i,f,g,o for unit (lane&7)
            const float iv = __shfl(gate, (lane & 7));
            const float fv = __shfl(gate, 8 + (lane & 7));
            const float gv = __shfl(gate, 16 + (lane & 7));
            const float ov = __shfl(gate, 24 + (lane & 7));
            const float cold = c_sh[lane & 7];
            const float cnew = sigmoidf_(fv) * cold + sigmoidf_(iv) * tanhf(gv);
            const float hnew = sigmoidf_(ov) * tanhf(cnew);
            if (lane < 8) {
                c_sh[lane] = cnew;
                __hip_atomic_store(hdst + b * UPW + lane, hnew,
                                   __ATOMIC_RELAXED, __HIP_MEMORY_SCOPE_AGENT);
            }
        }
        __syncthreads();  // drains vmcnt: h stores complete before flag

        // arrive
        if (t == 0) {
            __hip_atomic_store(&flags[b], s + 1, __ATOMIC_RELEASE, __HIP_MEMORY_SCOPE_AGENT);
        }
        // spin: thread t waits for WG t
        if (t < NWG) {
            while (__hip_atomic_load(&flags[t], __ATOMIC_RELAXED, __HIP_MEMORY_SCOPE_AGENT) < s + 1) {
                __builtin_amdgcn_s_sleep(2);
            }
        }
        __syncthreads();
    }

    // ---- epilogue: out[T-1] needs h after T updates ----
    if (b == ((TSTEPS - 1) & 255)) {
        float* hsrc = hbuf + (TSTEPS & 1) * HIDDEN;  // T even -> buffer 0
        const int i0 = t * 4;
        float v0 = __hip_atomic_load(hsrc + i0 + 0, __ATOMIC_RELAXED, __HIP_MEMORY_SCOPE_AGENT);
        float v1 = __hip_atomic_load(hsrc + i0 + 1, __ATOMIC_RELAXED, __HIP_MEMORY_SCOPE_AGENT);
        float v2 = __hip_atomic_load(hsrc + i0 + 2, __ATOMIC_RELAXED, __HIP_MEMORY_SCOPE_AGENT);
        float v3 = __hip_atomic_load(hsrc + i0 + 3, __ATOMIC_RELAXED, __HIP_MEMORY_SCOPE_AGENT);
        h_sh[i0 + 0] = v0; h_sh[i0 + 1] = v1; h_sh[i0 + 2] = v2; h_sh[i0 + 3] = v3;
        __syncthreads();

        float po0 = 0.0f, po1 = 0.0f;
        #pragma unroll
        for (int k = 0; k < CPT; ++k) {
            float hv = h_sh[col0 + k];
            po0 += hv * W_fc[col0 + k];
            po1 += hv * W_fc[HIDDEN + col0 + k];
        }
        #pragma unroll
        for (int m = 1; m < 64; m <<= 1) {
            po0 += __shfl_xor(po0, m);
            po1 += __shfl_xor(po1, m);
        }
        if (lane == 0) { outred[wave * 2 + 0] = po0; outred[wave * 2 + 1] = po1; }
        __syncthreads();
        if (t == 0) {
            float o0 = 0.0f, o1 = 0.0f;
            #pragma unroll
            for (int ww = 0; ww < 8; ++ww) { o0 += outred[ww * 2]; o1 += outred[ww * 2 + 1]; }
            out[(TSTEPS - 1) * 2 + 0] = 0.25f * o0 + b_fc[0];
            out[(TSTEPS - 1) * 2 + 1] = 0.25f * o1 + b_fc[1];
        }
    }
}

extern "C" void kernel_launch(void* const* d_in, const int* in_sizes, int n_in,
                              void* d_out, int out_size, void* d_ws, size_t ws_size,
                              hipStream_t stream) {
    const float* features = (const float*)d_in[0];
    const float* pc       = (const float*)d_in[1];
    const float* W_ih     = (const float*)d_in[2];
    const float* W_hh     = (const float*)d_in[3];
    const float* b_ih     = (const float*)d_in[4];
    const float* b_hh     = (const float*)d_in[5];
    const float* W_fc     = (const float*)d_in[6];
    const float* b_fc     = (const float*)d_in[7];

    float* out   = (float*)d_out;
    float* hbuf  = (float*)d_ws;
    int*   flags = (int*)((char*)d_ws + 2 * HIDDEN * sizeof(float));

    // flags must start at 0 every call (graph replays don't re-poison ws)
    hipMemsetAsync(flags, 0, NWG * sizeof(int), stream);

    hipLaunchKernelGGL(lstm_persistent, dim3(NWG), dim3(TPB), 0, stream,
                       features, pc, W_ih, W_hh, b_ih, b_hh, W_fc, b_fc,
                       out, hbuf, flags);
}

// Round 2
// 6582.760 us; speedup vs baseline: 1.3709x; 1.3709x over previous
//
#include <hip/hip_runtime.h>
#include <math.h>

#define HIDDEN 2048
#define TSTEPS 1024
#define NWG 256
#define TPB 512
#define UPW 8          // hidden units per WG
#define CPT 16         // columns per thread
#define MSG_STRIDE 32  // dwords per message line (128 B: [0]=epoch, [1..8]=h floats)

__device__ __forceinline__ float sigmoidf_(float x) { return 1.0f / (1.0f + __expf(-x)); }

__global__ __launch_bounds__(TPB, 2)
void lstm_persistent(const float* __restrict__ features,
                     const float* __restrict__ pc,
                     const float* __restrict__ W_ih,
                     const float* __restrict__ W_hh,
                     const float* __restrict__ b_ih,
                     const float* __restrict__ b_hh,
                     const float* __restrict__ W_fc,
                     const float* __restrict__ b_fc,
                     float* __restrict__ out,
                     int*   __restrict__ msg)   // NWG*MSG_STRIDE ints in ws, memset 0
{
    const int b    = blockIdx.x;
    const int t    = threadIdx.x;
    const int g    = t & 3;        // gate index 0..3 (i,f,g,o row blocks)
    const int cc   = t >> 2;       // column-chunk 0..127
    const int col0 = cc * CPT;
    const int lane = t & 63;
    const int wave = t >> 6;

    __shared__ float h_sh[HIDDEN];
    __shared__ float pc_sh[2 * TSTEPS];
    __shared__ float red[8 * 32];
    __shared__ float outred[8 * 2];

    // ---- one-time staging ----
    {   // point cloud -> LDS (2048 floats, 512 threads x float4)
        const float4* p4 = reinterpret_cast<const float4*>(pc);
        reinterpret_cast<float4*>(pc_sh)[t] = p4[t];
    }
    {   // initial h = features -> LDS (plain loads: input written before launch)
        const float4 f4 = reinterpret_cast<const float4*>(features)[t];
        h_sh[t * 4 + 0] = f4.x; h_sh[t * 4 + 1] = f4.y;
        h_sh[t * 4 + 2] = f4.z; h_sh[t * 4 + 3] = f4.w;
    }

    // W_hh slice -> registers: w[ji][k] = W_hh[g*2048 + b*8 + ji][col0 + k]
    float w[UPW][CPT];
    {
        const int baserow = g * HIDDEN + b * UPW;
        #pragma unroll
        for (int ji = 0; ji < UPW; ++ji) {
            const float4* src = reinterpret_cast<const float4*>(
                W_hh + (size_t)(baserow + ji) * HIDDEN + col0);
            float4 a0 = src[0], a1 = src[1], a2 = src[2], a3 = src[3];
            w[ji][0]  = a0.x; w[ji][1]  = a0.y; w[ji][2]  = a0.z; w[ji][3]  = a0.w;
            w[ji][4]  = a1.x; w[ji][5]  = a1.y; w[ji][6]  = a1.z; w[ji][7]  = a1.w;
            w[ji][8]  = a2.x; w[ji][9]  = a2.y; w[ji][10] = a2.z; w[ji][11] = a2.w;
            w[ji][12] = a3.x; w[ji][13] = a3.y; w[ji][14] = a3.z; w[ji][15] = a3.w;
        }
    }

    // per-row constants + cell state for wave 0 (row id l = lane&31: g' = l>>3, unit = l&7)
    float bias_r = 0.0f, wi0_r = 0.0f, wi1_r = 0.0f, creg = 0.0f;
    if (wave == 0) {
        const int l   = lane & 31;
        const int row = (l >> 3) * HIDDEN + b * UPW + (l & 7);
        bias_r = b_ih[row] + b_hh[row];
        wi0_r  = W_ih[row * 2 + 0];
        wi1_r  = W_ih[row * 2 + 1];
    }
    __syncthreads();

    // ---- recurrence ----
    for (int s = 0; s < TSTEPS; ++s) {
        // h_sh holds h_s here.

        // FMA phase: acc[ji] += w[ji][k] * h[col0+k]
        float hr[CPT];
        #pragma unroll
        for (int k = 0; k < CPT; k += 4) {
            float4 hv = *reinterpret_cast<const float4*>(h_sh + col0 + k);
            hr[k] = hv.x; hr[k + 1] = hv.y; hr[k + 2] = hv.z; hr[k + 3] = hv.w;
        }
        float acc[UPW];
        #pragma unroll
        for (int ji = 0; ji < UPW; ++ji) acc[ji] = 0.0f;
        #pragma unroll
        for (int k = 0; k < CPT; ++k) {
            #pragma unroll
            for (int ji = 0; ji < UPW; ++ji) acc[ji] += w[ji][k] * hr[k];
        }
        // intra-wave reduce across column-chunks (lanes sharing l&3)
        #pragma unroll
        for (int m = 4; m < 64; m <<= 1) {
            #pragma unroll
            for (int ji = 0; ji < UPW; ++ji) acc[ji] += __shfl_xor(acc[ji], m);
        }
        if (lane < 4) {
            #pragma unroll
            for (int ji = 0; ji < UPW; ++ji) red[wave * 32 + lane * 8 + ji] = acc[ji];
        }
        __syncthreads();   // (a) red[] ready

        // gates + publish on wave 0 (arrive-first)
        if (wave == 0) {
            const int l = lane & 31;   // row id: g' = l>>3, unit = l&7
            float sum = 0.0f;
            #pragma unroll
            for (int ww = 0; ww < 8; ++ww) sum += red[ww * 32 + l];
            const float x0 = pc_sh[2 * s], x1 = pc_sh[2 * s + 1];
            const float gate = sum + bias_r + wi0_r * x0 + wi1_r * x1;
            const float iv = __shfl(gate, (lane & 7));
            const float fv = __shfl(gate, 8 + (lane & 7));
            const float gv = __shfl(gate, 16 + (lane & 7));
            const float ov = __shfl(gate, 24 + (lane & 7));
            const float cnew = sigmoidf_(fv) * creg + sigmoidf_(iv) * tanhf(gv);
            const float hnew = sigmoidf_(ov) * tanhf(cnew);
            creg = cnew;   // lanes 0..31 redundantly track unit lane&7
            if (lane < 8) {
                __hip_atomic_store((float*)(msg + b * MSG_STRIDE + 1 + lane), hnew,
                                   __ATOMIC_RELAXED, __HIP_MEMORY_SCOPE_AGENT);
            }
            if (lane == 0) {
                // release drains the wave's h stores (vmcnt) before epoch becomes visible
                __hip_atomic_store(msg + b * MSG_STRIDE, s + 1,
                                   __ATOMIC_RELEASE, __HIP_MEMORY_SCOPE_AGENT);
            }
        }

        // fc for out[s-1] on rotating WG — overlaps with other WGs' barrier wait.
        // h_sh still holds h_s; out[s-1] = fc(h_s).
        if (s >= 1 && b == ((s - 1) & 255)) {
            float po0 = 0.0f, po1 = 0.0f;
            #pragma unroll
            for (int k = 0; k < CPT; ++k) {
                float hv = h_sh[col0 + k];
                po0 += hv * W_fc[col0 + k];
                po1 += hv * W_fc[HIDDEN + col0 + k];
            }
            #pragma unroll
            for (int m = 1; m < 64; m <<= 1) {
                po0 += __shfl_xor(po0, m);
                po1 += __shfl_xor(po1, m);
            }
            if (lane == 0) { outred[wave * 2 + 0] = po0; outred[wave * 2 + 1] = po1; }
            __syncthreads();
            if (t == 0) {
                float o0 = 0.0f, o1 = 0.0f;
                #pragma unroll
                for (int ww = 0; ww < 8; ++ww) { o0 += outred[ww * 2]; o1 += outred[ww * 2 + 1]; }
                out[(s - 1) * 2 + 0] = 0.25f * o0 + b_fc[0];
                out[(s - 1) * 2 + 1] = 0.25f * o1 + b_fc[1];
            }
        }
        __syncthreads();   // (c) everyone done reading h_sh

        // poll + restage h_{s+1}: one lane per producer line (256 distinct 128B lines)
        if (t < NWG) {
            int* line = msg + t * MSG_STRIDE;
            while (__hip_atomic_load(line, __ATOMIC_RELAXED, __HIP_MEMORY_SCOPE_AGENT) < s + 1) {
                __builtin_amdgcn_s_sleep(1);
            }
            float v[UPW];
            #pragma unroll
            for (int j = 0; j < UPW; ++j) {
                v[j] = __hip_atomic_load((float*)(line + 1 + j),
                                         __ATOMIC_RELAXED, __HIP_MEMORY_SCOPE_AGENT);
            }
            #pragma unroll
            for (int j = 0; j < UPW; ++j) h_sh[t * UPW + j] = v[j];
        }
        __syncthreads();   // (d) h_sh = h_{s+1}
    }

    // ---- epilogue: out[T-1] = fc(h_T); h_sh holds h_T ----
    if (b == ((TSTEPS - 1) & 255)) {
        float po0 = 0.0f, po1 = 0.0f;
        #pragma unroll
        for (int k = 0; k < CPT; ++k) {
            float hv = h_sh[col0 + k];
            po0 += hv * W_fc[col0 + k];
            po1 += hv * W_fc[HIDDEN + col0 + k];
        }
        #pragma unroll
        for (int m = 1; m < 64; m <<= 1) {
            po0 += __shfl_xor(po0, m);
            po1 += __shfl_xor(po1, m);
        }
        if (lane == 0) { outred[wave * 2 + 0] = po0; outred[wave * 2 + 1] = po1; }
        __syncthreads();
        if (t == 0) {
            float o0 = 0.0f, o1 = 0.0f;
            #pragma unroll
            for (int ww = 0; ww < 8; ++ww) { o0 += outred[ww * 2]; o1 += outred[ww * 2 + 1]; }
            out[(TSTEPS - 1) * 2 + 0] = 0.25f * o0 + b_fc[0];
            out[(TSTEPS - 1) * 2 + 1] = 0.25f * o1 + b_fc[1];
        }
    }
}

extern "C" void kernel_launch(void* const* d_in, const int* in_sizes, int n_in,
                              void* d_out, int out_size, void* d_ws, size_t ws_size,
                              hipStream_t stream) {
    const float* features = (const float*)d_in[0];
    const float* pc       = (const float*)d_in[1];
    const float* W_ih     = (const float*)d_in[2];
    const float* W_hh     = (const float*)d_in[3];
    const float* b_ih     = (const float*)d_in[4];
    const float* b_hh     = (const float*)d_in[5];
    const float* W_fc     = (const float*)d_in[6];
    const float* b_fc     = (const float*)d_in[7];

    float* out = (float*)d_out;
    int*   msg = (int*)d_ws;   // NWG * MSG_STRIDE ints = 32 KB

    // epochs must start at 0 every call (graph replays don't re-poison ws)
    hipMemsetAsync(msg, 0, NWG * MSG_STRIDE * sizeof(int), stream);

    hipLaunchKernelGGL(lstm_persistent, dim3(NWG), dim3(TPB), 0, stream,
                       features, pc, W_ih, W_hh, b_ih, b_hh, W_fc, b_fc,
                       out, msg);
}

// Round 3
// 6127.710 us; speedup vs baseline: 1.4727x; 1.0743x over previous
//
#include <hip/hip_runtime.h>
#include <math.h>
#include <stdint.h>

#define HIDDEN 2048
#define TSTEPS 1024
#define NWG 256
#define TPB 512
#define UPW 8           // hidden units per WG
#define CPT 16          // columns per thread
#define LINE_QW 6       // 64-bit words per message (16 halves + tags)
#define LINE_STRIDE_QW 16  // per line: 2 parity buffers x 8 qword slots

__device__ __forceinline__ float sigmoidf_(float x) { return 1.0f / (1.0f + __expf(-x)); }

__global__ __launch_bounds__(TPB, 2)
void lstm_persistent(const float* __restrict__ features,
                     const float* __restrict__ pc,
                     const float* __restrict__ W_ih,
                     const float* __restrict__ W_hh,
                     const float* __restrict__ b_ih,
                     const float* __restrict__ b_hh,
                     const float* __restrict__ W_fc,
                     const float* __restrict__ b_fc,
                     float* __restrict__ out,
                     uint64_t* __restrict__ msgq)  // NWG*LINE_STRIDE_QW qwords, memset 0
{
    const int b    = blockIdx.x;
    const int t    = threadIdx.x;
    const int g    = t & 3;        // gate block 0..3 (i,f,g,o)
    const int cc   = t >> 2;       // column-chunk 0..127
    const int col0 = cc * CPT;
    const int lane = t & 63;
    const int wave = t >> 6;

    __shared__ float h_sh[HIDDEN];
    __shared__ float pc_sh[2 * TSTEPS];
    __shared__ float red[8 * 32];
    __shared__ float outred[8 * 2];

    // ---- one-time staging ----
    {   // point cloud -> LDS
        const float4* p4 = reinterpret_cast<const float4*>(pc);
        reinterpret_cast<float4*>(pc_sh)[t] = p4[t];
    }
    {   // initial h = features -> LDS
        const float4 f4 = reinterpret_cast<const float4*>(features)[t];
        h_sh[t * 4 + 0] = f4.x; h_sh[t * 4 + 1] = f4.y;
        h_sh[t * 4 + 2] = f4.z; h_sh[t * 4 + 3] = f4.w;
    }

    // W_hh slice -> registers: w[ji][k] = W_hh[g*2048 + b*8 + ji][col0 + k]
    float w[UPW][CPT];
    {
        const int baserow = g * HIDDEN + b * UPW;
        #pragma unroll
        for (int ji = 0; ji < UPW; ++ji) {
            const float4* src = reinterpret_cast<const float4*>(
                W_hh + (size_t)(baserow + ji) * HIDDEN + col0);
            float4 a0 = src[0], a1 = src[1], a2 = src[2], a3 = src[3];
            w[ji][0]  = a0.x; w[ji][1]  = a0.y; w[ji][2]  = a0.z; w[ji][3]  = a0.w;
            w[ji][4]  = a1.x; w[ji][5]  = a1.y; w[ji][6]  = a1.z; w[ji][7]  = a1.w;
            w[ji][8]  = a2.x; w[ji][9]  = a2.y; w[ji][10] = a2.z; w[ji][11] = a2.w;
            w[ji][12] = a3.x; w[ji][13] = a3.y; w[ji][14] = a3.z; w[ji][15] = a3.w;
        }
    }

    // per-row constants + cell state for wave 0 (row id l = lane&31: gate = l>>3, unit = l&7)
    float bias_r = 0.0f, wi0_r = 0.0f, wi1_r = 0.0f, creg = 0.0f;
    if (wave == 0) {
        const int l   = lane & 31;
        const int row = (l >> 3) * HIDDEN + b * UPW + (l & 7);
        bias_r = b_ih[row] + b_hh[row];
        wi0_r  = W_ih[row * 2 + 0];
        wi1_r  = W_ih[row * 2 + 1];
    }
    __syncthreads();

    // ---- recurrence ----
    for (int s = 0; s < TSTEPS; ++s) {
        // h_sh holds h_s here.
        const int rot = (s >= 1) && (b == ((s - 1) & 255));   // this WG emits out[s-1]

        // FMA phase
        float hr[CPT];
        #pragma unroll
        for (int k = 0; k < CPT; k += 4) {
            float4 hv = *reinterpret_cast<const float4*>(h_sh + col0 + k);
            hr[k] = hv.x; hr[k + 1] = hv.y; hr[k + 2] = hv.z; hr[k + 3] = hv.w;
        }
        float acc[UPW];
        #pragma unroll
        for (int ji = 0; ji < UPW; ++ji) acc[ji] = 0.0f;
        #pragma unroll
        for (int k = 0; k < CPT; ++k) {
            #pragma unroll
            for (int ji = 0; ji < UPW; ++ji) acc[ji] += w[ji][k] * hr[k];
        }
        #pragma unroll
        for (int m = 4; m < 64; m <<= 1) {
            #pragma unroll
            for (int ji = 0; ji < UPW; ++ji) acc[ji] += __shfl_xor(acc[ji], m);
        }
        if (lane < 4) {
            #pragma unroll
            for (int ji = 0; ji < UPW; ++ji) red[wave * 32 + lane * 8 + ji] = acc[ji];
        }

        // fc partial for out[s-1] from registers (only rotating WG; rides barrier (a))
        if (rot) {
            float po0 = 0.0f, po1 = 0.0f;
            #pragma unroll
            for (int k = 0; k < CPT; ++k) {
                po0 += hr[k] * W_fc[col0 + k];
                po1 += hr[k] * W_fc[HIDDEN + col0 + k];
            }
            #pragma unroll
            for (int m = 1; m < 64; m <<= 1) {
                po0 += __shfl_xor(po0, m);
                po1 += __shfl_xor(po1, m);
            }
            if (lane == 0) { outred[wave * 2 + 0] = po0; outred[wave * 2 + 1] = po1; }
        }
        __syncthreads();   // (a) red[] + outred[] ready; h_sh free for restage

        if (wave == 0) {
            // final reduce + gates + publish
            const int l = lane & 31;
            float sum = 0.0f;
            #pragma unroll
            for (int ww = 0; ww < 8; ++ww) sum += red[ww * 32 + l];
            const float x0 = pc_sh[2 * s], x1 = pc_sh[2 * s + 1];
            const float gate = sum + bias_r + wi0_r * x0 + wi1_r * x1;
            const float iv = __shfl(gate, (lane & 7));
            const float fv = __shfl(gate, 8 + (lane & 7));
            const float gv = __shfl(gate, 16 + (lane & 7));
            const float ov = __shfl(gate, 24 + (lane & 7));
            const float cnew = sigmoidf_(fv) * creg + sigmoidf_(iv) * tanhf(gv);
            const float hnew = sigmoidf_(ov) * tanhf(cnew);
            creg = cnew;                       // lane holds unit lane&7
            const uint32_t hb = __float_as_uint(hnew);

            if (lane < UPW) h_sh[b * UPW + lane] = hnew;   // self-deliver

            // build self-validating qword: [tag16 | half(3l) | half(3l+1) | half(3l+2)]
            uint64_t v = ((uint64_t)(uint32_t)(s + 1)) << 48;
            #pragma unroll
            for (int i = 0; i < 3; ++i) {
                const int m  = 3 * lane + i;
                const int mc = (m < 16) ? m : 15;
                const uint32_t bits = __shfl(hb, mc >> 1);       // unit mc>>1 lives at lane mc>>1
                const uint32_t half = (mc & 1) ? (bits >> 16) : (bits & 0xFFFFu);
                if (m < 16) v |= (uint64_t)half << (32 - 16 * i);
            }
            if (lane < LINE_QW) {
                __hip_atomic_store(msgq + (size_t)b * LINE_STRIDE_QW + ((s + 1) & 1) * 8 + lane,
                                   v, __ATOMIC_RELAXED, __HIP_MEMORY_SCOPE_AGENT);
            }
        } else if (wave >= 4) {
            // poll + restage h_{s+1}: lane owns line (t-256)
            const int ln = t - 256;
            if (ln != b) {
                const uint64_t* lp = msgq + (size_t)ln * LINE_STRIDE_QW + ((s + 1) & 1) * 8;
                const uint32_t tagexp = (uint32_t)(s + 1);
                uint64_t q0, q1, q2, q3, q4, q5;
                for (;;) {
                    q0 = __hip_atomic_load(lp + 0, __ATOMIC_RELAXED, __HIP_MEMORY_SCOPE_AGENT);
                    q1 = __hip_atomic_load(lp + 1, __ATOMIC_RELAXED, __HIP_MEMORY_SCOPE_AGENT);
                    q2 = __hip_atomic_load(lp + 2, __ATOMIC_RELAXED, __HIP_MEMORY_SCOPE_AGENT);
                    q3 = __hip_atomic_load(lp + 3, __ATOMIC_RELAXED, __HIP_MEMORY_SCOPE_AGENT);
                    q4 = __hip_atomic_load(lp + 4, __ATOMIC_RELAXED, __HIP_MEMORY_SCOPE_AGENT);
                    q5 = __hip_atomic_load(lp + 5, __ATOMIC_RELAXED, __HIP_MEMORY_SCOPE_AGENT);
                    bool ok = ((uint32_t)(q0 >> 48) == tagexp) &
                              ((uint32_t)(q1 >> 48) == tagexp) &
                              ((uint32_t)(q2 >> 48) == tagexp) &
                              ((uint32_t)(q3 >> 48) == tagexp) &
                              ((uint32_t)(q4 >> 48) == tagexp) &
                              ((uint32_t)(q5 >> 48) == tagexp);
                    if (ok) break;
                }
                uint64_t qs[LINE_QW] = {q0, q1, q2, q3, q4, q5};
                uint32_t H[18];
                #pragma unroll
                for (int q = 0; q < LINE_QW; ++q) {
                    H[3 * q + 0] = (uint32_t)(qs[q] >> 32) & 0xFFFFu;
                    H[3 * q + 1] = (uint32_t)(qs[q] >> 16) & 0xFFFFu;
                    H[3 * q + 2] = (uint32_t)(qs[q] >>  0) & 0xFFFFu;
                }
                #pragma unroll
                for (int j = 0; j < UPW; ++j) {
                    h_sh[ln * UPW + j] = __uint_as_float(H[2 * j] | (H[2 * j + 1] << 16));
                }
            }
        }

        // out[s-1] final sum on wave 1 lane 0 (outred valid since (a))
        if (rot && t == 64) {
            float o0 = 0.0f, o1 = 0.0f;
            #pragma unroll
            for (int ww = 0; ww < 8; ++ww) { o0 += outred[ww * 2]; o1 += outred[ww * 2 + 1]; }
            out[(s - 1) * 2 + 0] = 0.25f * o0 + b_fc[0];
            out[(s - 1) * 2 + 1] = 0.25f * o1 + b_fc[1];
        }

        __syncthreads();   // (d) h_sh = h_{s+1}
    }

    // ---- epilogue: out[T-1] = fc(h_T); h_sh holds h_T ----
    if (b == ((TSTEPS - 1) & 255)) {
        float po0 = 0.0f, po1 = 0.0f;
        #pragma unroll
        for (int k = 0; k < CPT; ++k) {
            float hv = h_sh[col0 + k];
            po0 += hv * W_fc[col0 + k];
            po1 += hv * W_fc[HIDDEN + col0 + k];
        }
        #pragma unroll
        for (int m = 1; m < 64; m <<= 1) {
            po0 += __shfl_xor(po0, m);
            po1 += __shfl_xor(po1, m);
        }
        if (lane == 0) { outred[wave * 2 + 0] = po0; outred[wave * 2 + 1] = po1; }
        __syncthreads();
        if (t == 0) {
            float o0 = 0.0f, o1 = 0.0f;
            #pragma unroll
            for (int ww = 0; ww < 8; ++ww) { o0 += outred[ww * 2]; o1 += outred[ww * 2 + 1]; }
            out[(TSTEPS - 1) * 2 + 0] = 0.25f * o0 + b_fc[0];
            out[(TSTEPS - 1) * 2 + 1] = 0.25f * o1 + b_fc[1];
        }
    }
}

extern "C" void kernel_launch(void* const* d_in, const int* in_sizes, int n_in,
                              void* d_out, int out_size, void* d_ws, size_t ws_size,
                              hipStream_t stream) {
    const float* features = (const float*)d_in[0];
    const float* pc       = (const float*)d_in[1];
    const float* W_ih     = (const float*)d_in[2];
    const float* W_hh     = (const float*)d_in[3];
    const float* b_ih     = (const float*)d_in[4];
    const float* b_hh     = (const float*)d_in[5];
    const float* W_fc     = (const float*)d_in[6];
    const float* b_fc     = (const float*)d_in[7];

    float*    out  = (float*)d_out;
    uint64_t* msgq = (uint64_t*)d_ws;   // 256 lines * 16 qwords = 32 KB

    // tags must start != any (s+1) every call (graph replays don't re-poison ws)
    hipMemsetAsync(msgq, 0, NWG * LINE_STRIDE_QW * sizeof(uint64_t), stream);

    hipLaunchKernelGGL(lstm_persistent, dim3(NWG), dim3(TPB), 0, stream,
                       features, pc, W_ih, W_hh, b_ih, b_hh, W_fc, b_fc,
                       out, msgq);
}

// Round 4
// 5898.591 us; speedup vs baseline: 1.5299x; 1.0388x over previous
//
#include <hip/hip_runtime.h>
#include <math.h>
#include <stdint.h>

#define HIDDEN 2048
#define TSTEPS 1024
#define NWG 256
#define TPB 512
#define UPW 8           // hidden units per WG
#define CPT 16          // columns per thread

__device__ __forceinline__ float sigmoidf_(float x) { return 1.0f / (1.0f + __expf(-x)); }

// ======================= primary: cached history + one ready-counter =======================
__global__ __launch_bounds__(TPB, 2)
void lstm_hist(const float* __restrict__ features,
               const float* __restrict__ pc,
               const float* __restrict__ W_ih,
               const float* __restrict__ W_hh,
               const float* __restrict__ b_ih,
               const float* __restrict__ b_hh,
               const float* __restrict__ W_fc,
               const float* __restrict__ b_fc,
               float* __restrict__ out,
               int*   __restrict__ cnt,     // (TSTEPS+1) ints, memset 0 per launch
               float* __restrict__ hhist)   // (TSTEPS+1)*HIDDEN floats, slot s = h_s (slot 0 unused)
{
    const int b    = blockIdx.x;
    const int t    = threadIdx.x;
    const int g    = t & 3;        // gate block 0..3 (i,f,g,o)
    const int cc   = t >> 2;       // column-chunk 0..127
    const int col0 = cc * CPT;
    const int lane = t & 63;
    const int wave = t >> 6;

    __shared__ float pc_sh[2 * TSTEPS];
    __shared__ float red[8 * 32];
    __shared__ float outred[16];

    // Invalidate L1/L2 so plain cached reads of hhist can't see stale lines
    // from a previous graph replay. Runs once per launch per WG.
    __builtin_amdgcn_fence(__ATOMIC_ACQUIRE, "agent");

    // ---- one-time staging ----
    {   // point cloud -> LDS
        const float4* p4 = reinterpret_cast<const float4*>(pc);
        reinterpret_cast<float4*>(pc_sh)[t] = p4[t];
    }

    // W_hh slice -> registers: w[ji][k] = W_hh[g*2048 + b*8 + ji][col0 + k]
    float w[UPW][CPT];
    {
        const int baserow = g * HIDDEN + b * UPW;
        #pragma unroll
        for (int ji = 0; ji < UPW; ++ji) {
            const float4* src = reinterpret_cast<const float4*>(
                W_hh + (size_t)(baserow + ji) * HIDDEN + col0);
            float4 a0 = src[0], a1 = src[1], a2 = src[2], a3 = src[3];
            w[ji][0]  = a0.x; w[ji][1]  = a0.y; w[ji][2]  = a0.z; w[ji][3]  = a0.w;
            w[ji][4]  = a1.x; w[ji][5]  = a1.y; w[ji][6]  = a1.z; w[ji][7]  = a1.w;
            w[ji][8]  = a2.x; w[ji][9]  = a2.y; w[ji][10] = a2.z; w[ji][11] = a2.w;
            w[ji][12] = a3.x; w[ji][13] = a3.y; w[ji][14] = a3.z; w[ji][15] = a3.w;
        }
    }

    // per-row constants + cell state for wave 0 (row id l = lane&31: gate = l>>3, unit = l&7)
    float bias_r = 0.0f, wi0_r = 0.0f, wi1_r = 0.0f, creg = 0.0f;
    if (wave == 0) {
        const int l   = lane & 31;
        const int row = (l >> 3) * HIDDEN + b * UPW + (l & 7);
        bias_r = b_ih[row] + b_hh[row];
        wi0_r  = W_ih[row * 2 + 0];
        wi1_r  = W_ih[row * 2 + 1];
    }
    __syncthreads();

    // ---- recurrence ----
    for (int s = 0; s < TSTEPS; ++s) {
        const int rot = (s >= 1) && (b == ((s - 1) & 255));   // this WG emits out[s-1]
        const float* hsrc = (s == 0) ? features : (hhist + (size_t)s * HIDDEN);

        // h slice via plain cached loads (fresh address every step; XCD-L2 amortized)
        float hr[CPT];
        #pragma unroll
        for (int k = 0; k < CPT; k += 4) {
            float4 hv = *reinterpret_cast<const float4*>(hsrc + col0 + k);
            hr[k] = hv.x; hr[k + 1] = hv.y; hr[k + 2] = hv.z; hr[k + 3] = hv.w;
        }

        // FMA phase
        float acc[UPW];
        #pragma unroll
        for (int ji = 0; ji < UPW; ++ji) acc[ji] = 0.0f;
        #pragma unroll
        for (int k = 0; k < CPT; ++k) {
            #pragma unroll
            for (int ji = 0; ji < UPW; ++ji) acc[ji] += w[ji][k] * hr[k];
        }
        #pragma unroll
        for (int m = 4; m < 64; m <<= 1) {
            #pragma unroll
            for (int ji = 0; ji < UPW; ++ji) acc[ji] += __shfl_xor(acc[ji], m);
        }
        if (lane < 4) {
            #pragma unroll
            for (int ji = 0; ji < UPW; ++ji) red[wave * 32 + lane * 8 + ji] = acc[ji];
        }

        // fc partials for out[s-1] from registers (rotating WG; rides barrier (a))
        if (rot) {
            float po0 = 0.0f, po1 = 0.0f;
            #pragma unroll
            for (int k = 0; k < CPT; ++k) {
                po0 += hr[k] * W_fc[col0 + k];
                po1 += hr[k] * W_fc[HIDDEN + col0 + k];
            }
            #pragma unroll
            for (int m = 1; m < 64; m <<= 1) {
                po0 += __shfl_xor(po0, m);
                po1 += __shfl_xor(po1, m);
            }
            if (lane == 0) { outred[wave * 2 + 0] = po0; outred[wave * 2 + 1] = po1; }
        }
        __syncthreads();   // (a) red[] + outred[] ready

        if (wave == 0) {
            // final reduce + gates
            const int l = lane & 31;
            float sum = 0.0f;
            #pragma unroll
            for (int ww = 0; ww < 8; ++ww) sum += red[ww * 32 + l];
            const float x0 = pc_sh[2 * s], x1 = pc_sh[2 * s + 1];
            const float gate = sum + bias_r + wi0_r * x0 + wi1_r * x1;
            const float iv = __shfl(gate, (lane & 7));
            const float fv = __shfl(gate, 8 + (lane & 7));
            const float gv = __shfl(gate, 16 + (lane & 7));
            const float ov = __shfl(gate, 24 + (lane & 7));
            const float cnew = sigmoidf_(fv) * creg + sigmoidf_(iv) * tanhf(gv);
            const float hnew = sigmoidf_(ov) * tanhf(cnew);
            creg = cnew;   // lane tracks unit lane&7
            const uint32_t hb = __float_as_uint(hnew);

            // publish 8 floats as 4 write-through qword stores (full-wave shuffles)
            const uint32_t lo = __shfl(hb, 2 * (lane & 3));
            const uint32_t hi = __shfl(hb, 2 * (lane & 3) + 1);
            if (lane < 4) {
                const uint64_t qv = (uint64_t)lo | ((uint64_t)hi << 32);
                uint64_t* dst = reinterpret_cast<uint64_t*>(
                    hhist + (size_t)(s + 1) * HIDDEN + b * UPW) + lane;
                __hip_atomic_store(dst, qv, __ATOMIC_RELAXED, __HIP_MEMORY_SCOPE_AGENT);
            }
            if (lane == 0) {
                // data stores acked at the coherence point before the counter add issues
                asm volatile("s_waitcnt vmcnt(0)" ::: "memory");
                __hip_atomic_fetch_add(&cnt[s + 1], 1,
                                       __ATOMIC_RELAXED, __HIP_MEMORY_SCOPE_AGENT);
            }
        }

        // out[s-1] final sum (outred valid since (a))
        if (rot && t == 64) {
            float o0 = 0.0f, o1 = 0.0f;
            #pragma unroll
            for (int ww = 0; ww < 8; ++ww) { o0 += outred[ww * 2]; o1 += outred[ww * 2 + 1]; }
            out[(s - 1) * 2 + 0] = 0.25f * o0 + b_fc[0];
            out[(s - 1) * 2 + 1] = 0.25f * o1 + b_fc[1];
        }

        // single-lane poll of the step counter
        if (t == 0) {
            while (__hip_atomic_load(&cnt[s + 1], __ATOMIC_RELAXED,
                                     __HIP_MEMORY_SCOPE_AGENT) < NWG) {
                __builtin_amdgcn_s_sleep(1);
            }
        }
        __syncthreads();   // (b) h_{s+1} globally visible; cached loads safe
    }

    // ---- epilogue: out[T-1] = fc(h_T) ----
    if (b == ((TSTEPS - 1) & 255)) {
        const float* hsrc = hhist + (size_t)TSTEPS * HIDDEN;
        float po0 = 0.0f, po1 = 0.0f;
        #pragma unroll
        for (int k = 0; k < CPT; ++k) {
            const float hv = hsrc[col0 + k];
            po0 += hv * W_fc[col0 + k];
            po1 += hv * W_fc[HIDDEN + col0 + k];
        }
        #pragma unroll
        for (int m = 1; m < 64; m <<= 1) {
            po0 += __shfl_xor(po0, m);
            po1 += __shfl_xor(po1, m);
        }
        if (lane == 0) { outred[wave * 2 + 0] = po0; outred[wave * 2 + 1] = po1; }
        __syncthreads();
        if (t == 0) {
            float o0 = 0.0f, o1 = 0.0f;
            #pragma unroll
            for (int ww = 0; ww < 8; ++ww) { o0 += outred[ww * 2]; o1 += outred[ww * 2 + 1]; }
            out[(TSTEPS - 1) * 2 + 0] = 0.25f * o0 + b_fc[0];
            out[(TSTEPS - 1) * 2 + 1] = 0.25f * o1 + b_fc[1];
        }
    }
}

// ======================= fallback (round-3 kernel, needs only 32 KB ws) =======================
#define LINE_QW 6
#define LINE_STRIDE_QW 16

__global__ __launch_bounds__(TPB, 2)
void lstm_msg(const float* __restrict__ features,
              const float* __restrict__ pc,
              const float* __restrict__ W_ih,
              const float* __restrict__ W_hh,
              const float* __restrict__ b_ih,
              const float* __restrict__ b_hh,
              const float* __restrict__ W_fc,
              const float* __restrict__ b_fc,
              float* __restrict__ out,
              uint64_t* __restrict__ msgq)
{
    const int b    = blockIdx.x;
    const int t    = threadIdx.x;
    const int g    = t & 3;
    const int cc   = t >> 2;
    const int col0 = cc * CPT;
    const int lane = t & 63;
    const int wave = t >> 6;

    __shared__ float h_sh[HIDDEN];
    __shared__ float pc_sh[2 * TSTEPS];
    __shared__ float red[8 * 32];
    __shared__ float outred[16];

    {
        const float4* p4 = reinterpret_cast<const float4*>(pc);
        reinterpret_cast<float4*>(pc_sh)[t] = p4[t];
    }
    {
        const float4 f4 = reinterpret_cast<const float4*>(features)[t];
        h_sh[t * 4 + 0] = f4.x; h_sh[t * 4 + 1] = f4.y;
        h_sh[t * 4 + 2] = f4.z; h_sh[t * 4 + 3] = f4.w;
    }

    float w[UPW][CPT];
    {
        const int baserow = g * HIDDEN + b * UPW;
        #pragma unroll
        for (int ji = 0; ji < UPW; ++ji) {
            const float4* src = reinterpret_cast<const float4*>(
                W_hh + (size_t)(baserow + ji) * HIDDEN + col0);
            float4 a0 = src[0], a1 = src[1], a2 = src[2], a3 = src[3];
            w[ji][0]  = a0.x; w[ji][1]  = a0.y; w[ji][2]  = a0.z; w[ji][3]  = a0.w;
            w[ji][4]  = a1.x; w[ji][5]  = a1.y; w[ji][6]  = a1.z; w[ji][7]  = a1.w;
            w[ji][8]  = a2.x; w[ji][9]  = a2.y; w[ji][10] = a2.z; w[ji][11] = a2.w;
            w[ji][12] = a3.x; w[ji][13] = a3.y; w[ji][14] = a3.z; w[ji][15] = a3.w;
        }
    }

    float bias_r = 0.0f, wi0_r = 0.0f, wi1_r = 0.0f, creg = 0.0f;
    if (wave == 0) {
        const int l   = lane & 31;
        const int row = (l >> 3) * HIDDEN + b * UPW + (l & 7);
        bias_r = b_ih[row] + b_hh[row];
        wi0_r  = W_ih[row * 2 + 0];
        wi1_r  = W_ih[row * 2 + 1];
    }
    __syncthreads();

    for (int s = 0; s < TSTEPS; ++s) {
        const int rot = (s >= 1) && (b == ((s - 1) & 255));

        float hr[CPT];
        #pragma unroll
        for (int k = 0; k < CPT; k += 4) {
            float4 hv = *reinterpret_cast<const float4*>(h_sh + col0 + k);
            hr[k] = hv.x; hr[k + 1] = hv.y; hr[k + 2] = hv.z; hr[k + 3] = hv.w;
        }
        float acc[UPW];
        #pragma unroll
        for (int ji = 0; ji < UPW; ++ji) acc[ji] = 0.0f;
        #pragma unroll
        for (int k = 0; k < CPT; ++k) {
            #pragma unroll
            for (int ji = 0; ji < UPW; ++ji) acc[ji] += w[ji][k] * hr[k];
        }
        #pragma unroll
        for (int m = 4; m < 64; m <<= 1) {
            #pragma unroll
            for (int ji = 0; ji < UPW; ++ji) acc[ji] += __shfl_xor(acc[ji], m);
        }
        if (lane < 4) {
            #pragma unroll
            for (int ji = 0; ji < UPW; ++ji) red[wave * 32 + lane * 8 + ji] = acc[ji];
        }

        if (rot) {
            float po0 = 0.0f, po1 = 0.0f;
            #pragma unroll
            for (int k = 0; k < CPT; ++k) {
                po0 += hr[k] * W_fc[col0 + k];
                po1 += hr[k] * W_fc[HIDDEN + col0 + k];
            }
            #pragma unroll
            for (int m = 1; m < 64; m <<= 1) {
                po0 += __shfl_xor(po0, m);
                po1 += __shfl_xor(po1, m);
            }
            if (lane == 0) { outred[wave * 2 + 0] = po0; outred[wave * 2 + 1] = po1; }
        }
        __syncthreads();

        if (wave == 0) {
            const int l = lane & 31;
            float sum = 0.0f;
            #pragma unroll
            for (int ww = 0; ww < 8; ++ww) sum += red[ww * 32 + l];
            const float x0 = pc_sh[2 * s], x1 = pc_sh[2 * s + 1];
            const float gate = sum + bias_r + wi0_r * x0 + wi1_r * x1;
            const float iv = __shfl(gate, (lane & 7));
            const float fv = __shfl(gate, 8 + (lane & 7));
            const float gv = __shfl(gate, 16 + (lane & 7));
            const float ov = __shfl(gate, 24 + (lane & 7));
            const float cnew = sigmoidf_(fv) * creg + sigmoidf_(iv) * tanhf(gv);
            const float hnew = sigmoidf_(ov) * tanhf(cnew);
            creg = cnew;
            const uint32_t hb = __float_as_uint(hnew);

            if (lane < UPW) h_sh[b * UPW + lane] = hnew;

            uint64_t v = ((uint64_t)(uint32_t)(s + 1)) << 48;
            #pragma unroll
            for (int i = 0; i < 3; ++i) {
                const int m  = 3 * lane + i;
                const int mc = (m < 16) ? m : 15;
                const uint32_t bits = __shfl(hb, mc >> 1);
                const uint32_t half = (mc & 1) ? (bits >> 16) : (bits & 0xFFFFu);
                if (m < 16) v |= (uint64_t)half << (32 - 16 * i);
            }
            if (lane < LINE_QW) {
                __hip_atomic_store(msgq + (size_t)b * LINE_STRIDE_QW + ((s + 1) & 1) * 8 + lane,
                                   v, __ATOMIC_RELAXED, __HIP_MEMORY_SCOPE_AGENT);
            }
        } else if (wave >= 4) {
            const int ln = t - 256;
            if (ln != b) {
                const uint64_t* lp = msgq + (size_t)ln * LINE_STRIDE_QW + ((s + 1) & 1) * 8;
                const uint32_t tagexp = (uint32_t)(s + 1);
                uint64_t q0, q1, q2, q3, q4, q5;
                for (;;) {
                    q0 = __hip_atomic_load(lp + 0, __ATOMIC_RELAXED, __HIP_MEMORY_SCOPE_AGENT);
                    q1 = __hip_atomic_load(lp + 1, __ATOMIC_RELAXED, __HIP_MEMORY_SCOPE_AGENT);
                    q2 = __hip_atomic_load(lp + 2, __ATOMIC_RELAXED, __HIP_MEMORY_SCOPE_AGENT);
                    q3 = __hip_atomic_load(lp + 3, __ATOMIC_RELAXED, __HIP_MEMORY_SCOPE_AGENT);
                    q4 = __hip_atomic_load(lp + 4, __ATOMIC_RELAXED, __HIP_MEMORY_SCOPE_AGENT);
                    q5 = __hip_atomic_load(lp + 5, __ATOMIC_RELAXED, __HIP_MEMORY_SCOPE_AGENT);
                    bool ok = ((uint32_t)(q0 >> 48) == tagexp) &
                              ((uint32_t)(q1 >> 48) == tagexp) &
                              ((uint32_t)(q2 >> 48) == tagexp) &
                              ((uint32_t)(q3 >> 48) == tagexp) &
                              ((uint32_t)(q4 >> 48) == tagexp) &
                              ((uint32_t)(q5 >> 48) == tagexp);
                    if (ok) break;
                }
                uint64_t qs[LINE_QW] = {q0, q1, q2, q3, q4, q5};
                uint32_t H[18];
                #pragma unroll
                for (int q = 0; q < LINE_QW; ++q) {
                    H[3 * q + 0] = (uint32_t)(qs[q] >> 32) & 0xFFFFu;
                    H[3 * q + 1] = (uint32_t)(qs[q] >> 16) & 0xFFFFu;
                    H[3 * q + 2] = (uint32_t)(qs[q] >>  0) & 0xFFFFu;
                }
                #pragma unroll
                for (int j = 0; j < UPW; ++j) {
                    h_sh[ln * UPW + j] = __uint_as_float(H[2 * j] | (H[2 * j + 1] << 16));
                }
            }
        }

        if (rot && t == 64) {
            float o0 = 0.0f, o1 = 0.0f;
            #pragma unroll
            for (int ww = 0; ww < 8; ++ww) { o0 += outred[ww * 2]; o1 += outred[ww * 2 + 1]; }
            out[(s - 1) * 2 + 0] = 0.25f * o0 + b_fc[0];
            out[(s - 1) * 2 + 1] = 0.25f * o1 + b_fc[1];
        }

        __syncthreads();
    }

    if (b == ((TSTEPS - 1) & 255)) {
        float po0 = 0.0f, po1 = 0.0f;
        #pragma unroll
        for (int k = 0; k < CPT; ++k) {
            float hv = h_sh[col0 + k];
            po0 += hv * W_fc[col0 + k];
            po1 += hv * W_fc[HIDDEN + col0 + k];
        }
        #pragma unroll
        for (int m = 1; m < 64; m <<= 1) {
            po0 += __shfl_xor(po0, m);
            po1 += __shfl_xor(po1, m);
        }
        if (lane == 0) { outred[wave * 2 + 0] = po0; outred[wave * 2 + 1] = po1; }
        __syncthreads();
        if (t == 0) {
            float o0 = 0.0f, o1 = 0.0f;
            #pragma unroll
            for (int ww = 0; ww < 8; ++ww) { o0 += outred[ww * 2]; o1 += outred[ww * 2 + 1]; }
            out[(TSTEPS - 1) * 2 + 0] = 0.25f * o0 + b_fc[0];
            out[(TSTEPS - 1) * 2 + 1] = 0.25f * o1 + b_fc[1];
        }
    }
}

extern "C" void kernel_launch(void* const* d_in, const int* in_sizes, int n_in,
                              void* d_out, int out_size, void* d_ws, size_t ws_size,
                              hipStream_t stream) {
    const float* features = (const float*)d_in[0];
    const float* pc       = (const float*)d_in[1];
    const float* W_ih     = (const float*)d_in[2];
    const float* W_hh     = (const float*)d_in[3];
    const float* b_ih     = (const float*)d_in[4];
    const float* b_hh     = (const float*)d_in[5];
    const float* W_fc     = (const float*)d_in[6];
    const float* b_fc     = (const float*)d_in[7];
    float* out = (float*)d_out;

    const size_t cnt_bytes = (size_t)(TSTEPS + 1) * sizeof(int);
    const size_t hh_off    = (cnt_bytes + 255) & ~(size_t)255;
    const size_t need      = hh_off + (size_t)(TSTEPS + 1) * HIDDEN * sizeof(float);

    if (ws_size >= need) {
        int*   cnt   = (int*)d_ws;
        float* hhist = (float*)((char*)d_ws + hh_off);
        hipMemsetAsync(cnt, 0, cnt_bytes, stream);   // counters start at 0 every replay
        hipLaunchKernelGGL(lstm_hist, dim3(NWG), dim3(TPB), 0, stream,
                           features, pc, W_ih, W_hh, b_ih, b_hh, W_fc, b_fc,
                           out, cnt, hhist);
    } else {
        uint64_t* msgq = (uint64_t*)d_ws;
        hipMemsetAsync(msgq, 0, NWG * LINE_STRIDE_QW * sizeof(uint64_t), stream);
        hipLaunchKernelGGL(lstm_msg, dim3(NWG), dim3(TPB), 0, stream,
                           features, pc, W_ih, W_hh, b_ih, b_hh, W_fc, b_fc,
                           out, msgq);
    }
}

// Round 6
// 3595.361 us; speedup vs baseline: 2.5100x; 1.6406x over previous
//
#include <hip/hip_runtime.h>
#include <math.h>
#include <stdint.h>

#define HIDDEN 2048
#define TSTEPS 1024
#define NWG 256
#define TPB 512
#define UPW 8           // hidden units per WG
#define CPT 16          // columns per thread
#define FLAG_STRIDE 32  // ints per flag/go line (128 B)

__device__ __forceinline__ float sigmoidf_(float x) { return 1.0f / (1.0f + __expf(-x)); }

// grid = NWG. WG 255's wave 0 doubles as the barrier watcher during its wait phase.
__global__ __launch_bounds__(TPB, 2)
void lstm_hist(const float* __restrict__ features,
               const float* __restrict__ pc,
               const float* __restrict__ W_ih,
               const float* __restrict__ W_hh,
               const float* __restrict__ b_ih,
               const float* __restrict__ b_hh,
               const float* __restrict__ W_fc,
               const float* __restrict__ b_fc,
               float* __restrict__ out,
               int*   __restrict__ flags,   // NWG lines x FLAG_STRIDE ints, memset 0
               int*   __restrict__ go,      // 64 lines x FLAG_STRIDE ints, memset 0
               float* __restrict__ hhist)   // (TSTEPS+1)*HIDDEN floats, slot s = h_s
{
    const int b    = blockIdx.x;
    const int t    = threadIdx.x;
    const int lane = t & 63;
    const int wave = t >> 6;

    // Invalidate L1/L2 so plain cached reads of hhist can't see stale lines
    // from a previous graph replay.
    __builtin_amdgcn_fence(__ATOMIC_ACQUIRE, "agent");

    const int g    = t & 3;        // gate block 0..3 (i,f,g,o)
    const int cc   = t >> 2;       // column-chunk 0..127
    const int col0 = cc * CPT;
    const bool watcher = (b == NWG - 1) && (wave == 0);

    __shared__ float pc_sh[2 * TSTEPS];
    __shared__ float red[8 * 32];
    __shared__ float outred[16];

    {   // point cloud -> LDS
        const float4* p4 = reinterpret_cast<const float4*>(pc);
        reinterpret_cast<float4*>(pc_sh)[t] = p4[t];
    }

    // W_hh slice -> registers: w[ji][k] = W_hh[g*2048 + b*8 + ji][col0 + k]
    float w[UPW][CPT];
    {
        const int baserow = g * HIDDEN + b * UPW;
        #pragma unroll
        for (int ji = 0; ji < UPW; ++ji) {
            const float4* src = reinterpret_cast<const float4*>(
                W_hh + (size_t)(baserow + ji) * HIDDEN + col0);
            float4 a0 = src[0], a1 = src[1], a2 = src[2], a3 = src[3];
            w[ji][0]  = a0.x; w[ji][1]  = a0.y; w[ji][2]  = a0.z; w[ji][3]  = a0.w;
            w[ji][4]  = a1.x; w[ji][5]  = a1.y; w[ji][6]  = a1.z; w[ji][7]  = a1.w;
            w[ji][8]  = a2.x; w[ji][9]  = a2.y; w[ji][10] = a2.z; w[ji][11] = a2.w;
            w[ji][12] = a3.x; w[ji][13] = a3.y; w[ji][14] = a3.z; w[ji][15] = a3.w;
        }
    }

    // per-row constants + cell state for wave 0 (row id l = lane&31: gate = l>>3, unit = l&7)
    float bias_r = 0.0f, wi0_r = 0.0f, wi1_r = 0.0f, creg = 0.0f;
    if (wave == 0) {
        const int l   = lane & 31;
        const int row = (l >> 3) * HIDDEN + b * UPW + (l & 7);
        bias_r = b_ih[row] + b_hh[row];
        wi0_r  = W_ih[row * 2 + 0];
        wi1_r  = W_ih[row * 2 + 1];
    }
    __syncthreads();

    // ---- recurrence ----
    for (int s = 0; s < TSTEPS; ++s) {
        const int rot = (s >= 1) && (b == ((s - 1) & 255));   // this WG emits out[s-1]
        const float* hsrc = (s == 0) ? features : (hhist + (size_t)s * HIDDEN);

        // h slice via plain cached loads (fresh address every step)
        float hr[CPT];
        #pragma unroll
        for (int k = 0; k < CPT; k += 4) {
            float4 hv = *reinterpret_cast<const float4*>(hsrc + col0 + k);
            hr[k] = hv.x; hr[k + 1] = hv.y; hr[k + 2] = hv.z; hr[k + 3] = hv.w;
        }

        // FMA phase
        float acc[UPW];
        #pragma unroll
        for (int ji = 0; ji < UPW; ++ji) acc[ji] = 0.0f;
        #pragma unroll
        for (int k = 0; k < CPT; ++k) {
            #pragma unroll
            for (int ji = 0; ji < UPW; ++ji) acc[ji] += w[ji][k] * hr[k];
        }
        #pragma unroll
        for (int m = 4; m < 64; m <<= 1) {
            #pragma unroll
            for (int ji = 0; ji < UPW; ++ji) acc[ji] += __shfl_xor(acc[ji], m);
        }
        if (lane < 4) {
            #pragma unroll
            for (int ji = 0; ji < UPW; ++ji) red[wave * 32 + lane * 8 + ji] = acc[ji];
        }

        // fc partials for out[s-1] from registers (rotating WG; rides barrier (a))
        if (rot) {
            float po0 = 0.0f, po1 = 0.0f;
            #pragma unroll
            for (int k = 0; k < CPT; ++k) {
                po0 += hr[k] * W_fc[col0 + k];
                po1 += hr[k] * W_fc[HIDDEN + col0 + k];
            }
            #pragma unroll
            for (int m = 1; m < 64; m <<= 1) {
                po0 += __shfl_xor(po0, m);
                po1 += __shfl_xor(po1, m);
            }
            if (lane == 0) { outred[wave * 2 + 0] = po0; outred[wave * 2 + 1] = po1; }
        }
        __syncthreads();   // (a) red[] + outred[] ready

        if (wave == 0) {
            // final reduce + gates
            const int l = lane & 31;
            float sum = 0.0f;
            #pragma unroll
            for (int ww = 0; ww < 8; ++ww) sum += red[ww * 32 + l];
            const float x0 = pc_sh[2 * s], x1 = pc_sh[2 * s + 1];
            const float gate = sum + bias_r + wi0_r * x0 + wi1_r * x1;
            const float iv = __shfl(gate, (lane & 7));
            const float fv = __shfl(gate, 8 + (lane & 7));
            const float gv = __shfl(gate, 16 + (lane & 7));
            const float ov = __shfl(gate, 24 + (lane & 7));
            const float cnew = sigmoidf_(fv) * creg + sigmoidf_(iv) * tanhf(gv);
            const float hnew = sigmoidf_(ov) * tanhf(cnew);
            creg = cnew;   // lane tracks unit lane&7
            const uint32_t hb = __float_as_uint(hnew);

            // publish 8 floats as 4 write-through qword stores
            const uint32_t lo = __shfl(hb, 2 * (lane & 3));
            const uint32_t hi = __shfl(hb, 2 * (lane & 3) + 1);
            if (lane < 4) {
                const uint64_t qv = (uint64_t)lo | ((uint64_t)hi << 32);
                uint64_t* dst = reinterpret_cast<uint64_t*>(
                    hhist + (size_t)(s + 1) * HIDDEN + b * UPW) + lane;
                __hip_atomic_store(dst, qv, __ATOMIC_RELAXED, __HIP_MEMORY_SCOPE_AGENT);
            }
            // data acked at the coherence point before the flag becomes visible
            asm volatile("s_waitcnt vmcnt(0)" ::: "memory");
            if (lane == 0) {
                __hip_atomic_store(flags + (size_t)b * FLAG_STRIDE, s + 1,
                                   __ATOMIC_RELAXED, __HIP_MEMORY_SCOPE_AGENT);
            }
        }

        // out[s-1] final sum (outred valid since (a))
        if (rot && t == 64) {
            float o0 = 0.0f, o1 = 0.0f;
            #pragma unroll
            for (int ww = 0; ww < 8; ++ww) { o0 += outred[ww * 2]; o1 += outred[ww * 2 + 1]; }
            out[(s - 1) * 2 + 0] = 0.25f * o0 + b_fc[0];
            out[(s - 1) * 2 + 1] = 0.25f * o1 + b_fc[1];
        }

        // ---- watcher duty: WG 255 wave 0 relays the global barrier ----
        if (watcher) {
            const int l4 = lane * 4;
            const int* f0p = flags + (size_t)(l4 + 0) * FLAG_STRIDE;
            const int* f1p = flags + (size_t)(l4 + 1) * FLAG_STRIDE;
            const int* f2p = flags + (size_t)(l4 + 2) * FLAG_STRIDE;
            const int* f3p = flags + (size_t)(l4 + 3) * FLAG_STRIDE;
            for (;;) {
                // 4 independent in-flight loads; exactly 1 poller per flag line
                const int f0 = __hip_atomic_load(f0p, __ATOMIC_RELAXED, __HIP_MEMORY_SCOPE_AGENT);
                const int f1 = __hip_atomic_load(f1p, __ATOMIC_RELAXED, __HIP_MEMORY_SCOPE_AGENT);
                const int f2 = __hip_atomic_load(f2p, __ATOMIC_RELAXED, __HIP_MEMORY_SCOPE_AGENT);
                const int f3 = __hip_atomic_load(f3p, __ATOMIC_RELAXED, __HIP_MEMORY_SCOPE_AGENT);
                const bool ok = (f0 >= s + 1) & (f1 >= s + 1) & (f2 >= s + 1) & (f3 >= s + 1);
                if (__all(ok)) break;
            }
            // fan-out: 64 go lines, 1 writer each, <=4 pollers each
            __hip_atomic_store(go + (size_t)lane * FLAG_STRIDE, s + 1,
                               __ATOMIC_RELAXED, __HIP_MEMORY_SCOPE_AGENT);
        }

        // wait for go (<=4 pollers per go line; WG 255 sees its own store immediately)
        if (t == 0) {
            const int* gop = go + (size_t)(b >> 2) * FLAG_STRIDE;
            while (__hip_atomic_load(gop, __ATOMIC_RELAXED,
                                     __HIP_MEMORY_SCOPE_AGENT) < s + 1) {
                __builtin_amdgcn_s_sleep(1);
            }
        }
        __syncthreads();   // (b) h_{s+1} globally visible; cached loads safe
    }

    // ---- epilogue: out[T-1] = fc(h_T) ----
    if (b == ((TSTEPS - 1) & 255)) {
        const float* hsrc = hhist + (size_t)TSTEPS * HIDDEN;
        float po0 = 0.0f, po1 = 0.0f;
        #pragma unroll
        for (int k = 0; k < CPT; ++k) {
            const float hv = hsrc[col0 + k];
            po0 += hv * W_fc[col0 + k];
            po1 += hv * W_fc[HIDDEN + col0 + k];
        }
        #pragma unroll
        for (int m = 1; m < 64; m <<= 1) {
            po0 += __shfl_xor(po0, m);
            po1 += __shfl_xor(po1, m);
        }
        if (lane == 0) { outred[wave * 2 + 0] = po0; outred[wave * 2 + 1] = po1; }
        __syncthreads();
        if (t == 0) {
            float o0 = 0.0f, o1 = 0.0f;
            #pragma unroll
            for (int ww = 0; ww < 8; ++ww) { o0 += outred[ww * 2]; o1 += outred[ww * 2 + 1]; }
            out[(TSTEPS - 1) * 2 + 0] = 0.25f * o0 + b_fc[0];
            out[(TSTEPS - 1) * 2 + 1] = 0.25f * o1 + b_fc[1];
        }
    }
}

extern "C" void kernel_launch(void* const* d_in, const int* in_sizes, int n_in,
                              void* d_out, int out_size, void* d_ws, size_t ws_size,
                              hipStream_t stream) {
    const float* features = (const float*)d_in[0];
    const float* pc       = (const float*)d_in[1];
    const float* W_ih     = (const float*)d_in[2];
    const float* W_hh     = (const float*)d_in[3];
    const float* b_ih     = (const float*)d_in[4];
    const float* b_hh     = (const float*)d_in[5];
    const float* W_fc     = (const float*)d_in[6];
    const float* b_fc     = (const float*)d_in[7];
    float* out = (float*)d_out;

    const size_t flags_bytes = (size_t)NWG * FLAG_STRIDE * sizeof(int);  // 32 KB
    const size_t go_bytes    = (size_t)64 * FLAG_STRIDE * sizeof(int);   //  8 KB
    const size_t hh_off      = flags_bytes + go_bytes;                   // 40 KB (256B-aligned)

    int*   flags = (int*)d_ws;
    int*   go    = (int*)((char*)d_ws + flags_bytes);
    float* hhist = (float*)((char*)d_ws + hh_off);

    // flags/go must start at 0 every call (graph replays don't re-poison ws)
    hipMemsetAsync(d_ws, 0, hh_off, stream);

    hipLaunchKernelGGL(lstm_hist, dim3(NWG), dim3(TPB), 0, stream,
                       features, pc, W_ih, W_hh, b_ih, b_hh, W_fc, b_fc,
                       out, flags, go, hhist);
}